// Round 7
// baseline (249.285 us; speedup 1.0000x reference)
//
#include <hip/hip_runtime.h>

#define N_ZONE 100000
#define E_ZONE 2000000
#define N_OUT  50000
#define E_OUT  1000000
#define N_GND  50000
#define E_GND  1000000
#define HID    64
#define N_TOT   (N_ZONE + N_OUT + N_GND)     // 200000
#define E_TOTAL (E_ZONE + E_OUT + E_GND)     // 4000000

// ---- binning geometry ----
#define RANGE   2048
#define RSHIFT  11
#define NBZ     49
#define NBO     25
#define NBG     25
#define NBUCKET (NBZ + NBO + NBG)            // 99
#define SL_D    16                           // deg slices per bucket
#define SL_S    8                            // s slices per bucket
#define CAP     49152                        // bucket capacity (mean ~40.6k, sigma ~200)
#define OUT_PAD_BASE (NBZ * RANGE)           // 100352
#define GND_PAD_BASE ((NBZ + NBO) * RANGE)   // 151552
#define PAD_TOT      (NBUCKET * RANGE)       // 202752

#define CHUNK  4096
#define NCHUNK ((E_TOTAL + CHUNK - 1) / CHUNK)   // 977

// ---- ws layout (32-bit words), no overlays ----
#define WCUR  0                               // u32 CUR[128]
#define WREC  128                             // uint2 rec[99*CAP]
#define WPDEG (WREC + 2 * NBUCKET * CAP)
#define WPSZ  (WPDEG + NBUCKET * SL_D * RANGE)
#define WPSO  (WPSZ + NBZ * SL_S * RANGE * 2)
#define WPSG  (WPSO + NBO * SL_S * RANGE * 3)
#define WDINV (WPSG + NBG * SL_S * RANGE)
#define WYZ   (WDINV + PAD_TOT)
#define WYO   (WYZ + 2 * N_ZONE)
#define WYG   (WYO + 4 * N_OUT)
#define WTOT  (WYG + N_GND)                   // ~16.9M words = 67.5 MB (<82.3 proven)
#define FAST_WS_BYTES ((size_t)WTOT * 4)

// K1: single-pass bin: stage chunk in LDS ordered by bucket, bump-allocate into
// fixed-CAP bucket regions; u8 bucket-id array avoids binary search on copy-out.
__global__ void k_bin(const int* __restrict__ eiz, const float* __restrict__ wz,
                      const int* __restrict__ eio, const float* __restrict__ wo,
                      const int* __restrict__ eig, const float* __restrict__ wg,
                      unsigned* __restrict__ cur, uint2* __restrict__ rec) {
    __shared__ unsigned la[CHUNK];
    __shared__ float    lw[CHUNK];
    __shared__ unsigned char lbk[CHUNK];
    __shared__ unsigned hist[NBUCKET];
    __shared__ unsigned sbase[NBUCKET + 1];
    __shared__ unsigned gbase[NBUCKET];
    int tid = threadIdx.x;
    for (int b = tid; b < NBUCKET; b += 256) hist[b] = 0;
    __syncthreads();
    int t0 = blockIdx.x * CHUNK;
    unsigned mya[CHUNK / 256], mybk[CHUNK / 256], myr[CHUNK / 256];
    float myw[CHUNK / 256];
#pragma unroll
    for (int i = 0; i < CHUNK / 256; i++) {
        int t = t0 + i * 256 + tid;
        unsigned b = 0xFFFFFFFFu;
        if (t < E_TOTAL) {
            int row, col; float w;
            if (t < E_ZONE) { row = eiz[t]; col = eiz[E_ZONE + t]; w = wz[t]; b = col >> RSHIFT; }
            else if (t < E_ZONE + E_OUT) { int e = t - E_ZONE; row = eio[e]; col = eio[E_OUT + e]; w = wo[e]; b = NBZ + (col >> RSHIFT); }
            else { int e = t - E_ZONE - E_OUT; row = eig[e]; col = eig[E_GND + e]; w = wg[e]; b = NBZ + NBO + (col >> RSHIFT); }
            mya[i] = ((unsigned)(col & (RANGE - 1)) << 17) | (unsigned)row;
            myw[i] = w;
            myr[i] = atomicAdd(&hist[b], 1u);
        }
        mybk[i] = b;
    }
    __syncthreads();
    if (tid == 0) {
        unsigned acc = 0;
        for (int b = 0; b < NBUCKET; b++) { sbase[b] = acc; acc += hist[b]; }
        sbase[NBUCKET] = acc;
    }
    __syncthreads();
    if (tid < NBUCKET)
        gbase[tid] = hist[tid] ? atomicAdd(&cur[tid], hist[tid]) : 0u;
#pragma unroll
    for (int i = 0; i < CHUNK / 256; i++) {
        if (mybk[i] < NBUCKET) {
            unsigned p = sbase[mybk[i]] + myr[i];
            la[p] = mya[i]; lw[p] = myw[i]; lbk[p] = (unsigned char)mybk[i];
        }
    }
    __syncthreads();
    unsigned total = sbase[NBUCKET];
    for (unsigned p = tid; p < total; p += 256) {
        int lo = lbk[p];
        unsigned idx = (unsigned)lo * CAP + gbase[lo] + (p - sbase[lo]);
        rec[idx] = make_uint2(la[p], __float_as_uint(lw[p]));
    }
}

// K2: per (bucket, deg-slice): LDS-accumulate deg, batch-4 loads, dense partial out
__global__ void k_degp(const uint2* __restrict__ rec, const unsigned* __restrict__ cur,
                       float* __restrict__ pdeg) {
    __shared__ float deg[RANGE];
    int r = blockIdx.x / SL_D, sl = blockIdx.x % SL_D, tid = threadIdx.x;
    for (int i = tid; i < RANGE; i += 256) deg[i] = 0.0f;
    __syncthreads();
    unsigned c = cur[r];
    size_t b0 = (size_t)r * CAP;
    unsigned per = (((c + SL_D - 1) / SL_D) + 3) & ~3u;
    unsigned s0 = sl * per, s1 = s0 + per; if (s1 > c) s1 = c;
    unsigned jq = s1 & ~3u;
    for (unsigned j = s0 + (tid << 2); j < jq; j += 1024) {
        uint2 q0 = rec[b0 + j], q1 = rec[b0 + j + 1], q2 = rec[b0 + j + 2], q3 = rec[b0 + j + 3];
        atomicAdd(&deg[q0.x >> 17], __uint_as_float(q0.y));
        atomicAdd(&deg[q1.x >> 17], __uint_as_float(q1.y));
        atomicAdd(&deg[q2.x >> 17], __uint_as_float(q2.y));
        atomicAdd(&deg[q3.x >> 17], __uint_as_float(q3.y));
    }
    if (s0 <= jq && jq < s1 && tid < (int)(s1 - jq)) {
        uint2 q = rec[b0 + jq + tid];
        atomicAdd(&deg[q.x >> 17], __uint_as_float(q.y));
    }
    __syncthreads();
    float* o = pdeg + (size_t)blockIdx.x * RANGE;
    for (int i = tid * 4; i < RANGE; i += 1024)
        *(float4*)&o[i] = *(float4*)&deg[i];
}

// K3: reduce deg partials -> dinv; y = dinv * x
__global__ void k_dinvy(const float* __restrict__ xz, const float* __restrict__ xo,
                        const float* __restrict__ xg, float* __restrict__ ws) {
    int p = blockIdx.x * blockDim.x + threadIdx.x;
    if (p >= PAD_TOT) return;
    int r = p >> RSHIFT, i = p & (RANGE - 1);
    float d = 1.0f;
#pragma unroll
    for (int sl = 0; sl < SL_D; sl++)
        d += ws[WPDEG + (size_t)(r * SL_D + sl) * RANGE + i];
    float di = rsqrtf(d);
    ws[WDINV + p] = di;
    if (p < OUT_PAD_BASE) {
        if (p < N_ZONE) {
            ws[WYZ + 2 * p]     = di * xz[2 * p];
            ws[WYZ + 2 * p + 1] = di * xz[2 * p + 1];
        }
    } else if (p < GND_PAD_BASE) {
        int idx = p - OUT_PAD_BASE;
        if (idx < N_OUT) {
            ws[WYO + 4 * idx]     = di * xo[3 * idx];
            ws[WYO + 4 * idx + 1] = di * xo[3 * idx + 1];
            ws[WYO + 4 * idx + 2] = di * xo[3 * idx + 2];
            ws[WYO + 4 * idx + 3] = 0.0f;
        }
    } else {
        int idx = p - GND_PAD_BASE;
        if (idx < N_GND) ws[WYG + idx] = di * xg[idx];
    }
}

// K4: per (bucket, s-slice): LDS-accumulate s[col][ch] += w*y[row][ch], batch-4
__global__ void k_sp(float* __restrict__ ws) {
    __shared__ __align__(16) float s[RANGE * 3];     // 24 KB
    int r = blockIdx.x / SL_S, sl = blockIdx.x % SL_S, tid = threadIdx.x;
    const unsigned* cur = (const unsigned*)(ws + WCUR);
    const uint2* rec = (const uint2*)(ws + WREC);
    int ch, rg; size_t yoff, psoff;
    if (r < NBZ)            { ch = 2; rg = r;             yoff = WYZ; psoff = WPSZ; }
    else if (r < NBZ + NBO) { ch = 3; rg = r - NBZ;       yoff = WYO; psoff = WPSO; }
    else                    { ch = 1; rg = r - NBZ - NBO; yoff = WYG; psoff = WPSG; }
    int tot = RANGE * ch;
    for (int i = tid; i < tot; i += 256) s[i] = 0.0f;
    __syncthreads();
    unsigned c = cur[r];
    size_t b0 = (size_t)r * CAP;
    unsigned per = (((c + SL_S - 1) / SL_S) + 3) & ~3u;
    unsigned s0 = sl * per, s1 = s0 + per; if (s1 > c) s1 = c;
    unsigned jq = s1 & ~3u;
    if (ch == 2) {
        const float2* y = (const float2*)(ws + yoff);
        for (unsigned j = s0 + (tid << 2); j < jq; j += 1024) {
            uint2 q0 = rec[b0 + j], q1 = rec[b0 + j + 1], q2 = rec[b0 + j + 2], q3 = rec[b0 + j + 3];
            float2 y0 = y[q0.x & 0x1FFFFu], y1 = y[q1.x & 0x1FFFFu];
            float2 y2 = y[q2.x & 0x1FFFFu], y3 = y[q3.x & 0x1FFFFu];
            float w0 = __uint_as_float(q0.y), w1 = __uint_as_float(q1.y);
            float w2 = __uint_as_float(q2.y), w3 = __uint_as_float(q3.y);
            atomicAdd(&s[(q0.x >> 17) * 2],     w0 * y0.x);
            atomicAdd(&s[(q0.x >> 17) * 2 + 1], w0 * y0.y);
            atomicAdd(&s[(q1.x >> 17) * 2],     w1 * y1.x);
            atomicAdd(&s[(q1.x >> 17) * 2 + 1], w1 * y1.y);
            atomicAdd(&s[(q2.x >> 17) * 2],     w2 * y2.x);
            atomicAdd(&s[(q2.x >> 17) * 2 + 1], w2 * y2.y);
            atomicAdd(&s[(q3.x >> 17) * 2],     w3 * y3.x);
            atomicAdd(&s[(q3.x >> 17) * 2 + 1], w3 * y3.y);
        }
        if (s0 <= jq && jq < s1 && tid < (int)(s1 - jq)) {
            uint2 q = rec[b0 + jq + tid];
            float2 yv = y[q.x & 0x1FFFFu];
            float w = __uint_as_float(q.y);
            atomicAdd(&s[(q.x >> 17) * 2],     w * yv.x);
            atomicAdd(&s[(q.x >> 17) * 2 + 1], w * yv.y);
        }
    } else if (ch == 3) {
        const float4* y = (const float4*)(ws + yoff);
        for (unsigned j = s0 + (tid << 2); j < jq; j += 1024) {
            uint2 q0 = rec[b0 + j], q1 = rec[b0 + j + 1], q2 = rec[b0 + j + 2], q3 = rec[b0 + j + 3];
            float4 y0 = y[q0.x & 0x1FFFFu], y1 = y[q1.x & 0x1FFFFu];
            float4 y2 = y[q2.x & 0x1FFFFu], y3 = y[q3.x & 0x1FFFFu];
            float w0 = __uint_as_float(q0.y), w1 = __uint_as_float(q1.y);
            float w2 = __uint_as_float(q2.y), w3 = __uint_as_float(q3.y);
            unsigned c0 = (q0.x >> 17) * 3, c1 = (q1.x >> 17) * 3, c2 = (q2.x >> 17) * 3, c3 = (q3.x >> 17) * 3;
            atomicAdd(&s[c0], w0 * y0.x); atomicAdd(&s[c0 + 1], w0 * y0.y); atomicAdd(&s[c0 + 2], w0 * y0.z);
            atomicAdd(&s[c1], w1 * y1.x); atomicAdd(&s[c1 + 1], w1 * y1.y); atomicAdd(&s[c1 + 2], w1 * y1.z);
            atomicAdd(&s[c2], w2 * y2.x); atomicAdd(&s[c2 + 1], w2 * y2.y); atomicAdd(&s[c2 + 2], w2 * y2.z);
            atomicAdd(&s[c3], w3 * y3.x); atomicAdd(&s[c3 + 1], w3 * y3.y); atomicAdd(&s[c3 + 2], w3 * y3.z);
        }
        if (s0 <= jq && jq < s1 && tid < (int)(s1 - jq)) {
            uint2 q = rec[b0 + jq + tid];
            float4 yv = y[q.x & 0x1FFFFu];
            float w = __uint_as_float(q.y);
            unsigned cc = (q.x >> 17) * 3;
            atomicAdd(&s[cc], w * yv.x); atomicAdd(&s[cc + 1], w * yv.y); atomicAdd(&s[cc + 2], w * yv.z);
        }
    } else {
        const float* y = ws + yoff;
        for (unsigned j = s0 + (tid << 2); j < jq; j += 1024) {
            uint2 q0 = rec[b0 + j], q1 = rec[b0 + j + 1], q2 = rec[b0 + j + 2], q3 = rec[b0 + j + 3];
            float y0 = y[q0.x & 0x1FFFFu], y1 = y[q1.x & 0x1FFFFu];
            float y2 = y[q2.x & 0x1FFFFu], y3 = y[q3.x & 0x1FFFFu];
            atomicAdd(&s[q0.x >> 17], __uint_as_float(q0.y) * y0);
            atomicAdd(&s[q1.x >> 17], __uint_as_float(q1.y) * y1);
            atomicAdd(&s[q2.x >> 17], __uint_as_float(q2.y) * y2);
            atomicAdd(&s[q3.x >> 17], __uint_as_float(q3.y) * y3);
        }
        if (s0 <= jq && jq < s1 && tid < (int)(s1 - jq)) {
            uint2 q = rec[b0 + jq + tid];
            atomicAdd(&s[q.x >> 17], __uint_as_float(q.y) * y[q.x & 0x1FFFFu]);
        }
    }
    __syncthreads();
    float* o = ws + psoff + (size_t)(rg * SL_S + sl) * tot;
    for (int i = tid * 4; i < tot; i += 1024)
        *(float4*)&o[i] = *(float4*)&s[i];
}

// K5 (fused k_u + k_fin2): per node-tile block, reduce slice-partials -> u in LDS,
// then out = relu(u @ W + b) with float4 stores.
#define NBKZ ((N_ZONE + 127) / 128)   // 782
#define NBKO ((N_OUT + 63) / 64)      // 782
#define NBKG ((N_GND + 255) / 256)    // 196
__global__ void k_fin3(const float* __restrict__ ws,
                       const float* __restrict__ Wz, const float* __restrict__ bz,
                       const float* __restrict__ Wo, const float* __restrict__ bo,
                       const float* __restrict__ Wg, const float* __restrict__ bg,
                       float* __restrict__ out) {
    __shared__ float su[256];
    int bid = blockIdx.x, tid = threadIdx.x;
    if (bid < NBKZ) {                     // zone: 128 nodes/block, ch=2
        int n0 = bid * 128;
        int n = n0 + (tid >> 1), c = tid & 1;
        if (n < N_ZONE) {
            int r = n >> RSHIFT, i = n & (RANGE - 1);
            float sum = ws[WYZ + 2 * n + c];
#pragma unroll
            for (int sl = 0; sl < SL_S; sl++)
                sum += ws[WPSZ + (size_t)(r * SL_S + sl) * (RANGE * 2) + 2 * i + c];
            su[tid] = ws[WDINV + n] * sum;
        }
        __syncthreads();
#pragma unroll
        for (int k = 0; k < 8; k++) {
            int f = tid + k * 256;
            int node = f >> 4, jb = (f & 15) << 2;
            int n2 = n0 + node;
            if (n2 < N_ZONE) {
                float u0 = su[2 * node], u1 = su[2 * node + 1];
                float4 w0 = *(const float4*)(Wz + jb);
                float4 w1 = *(const float4*)(Wz + HID + jb);
                float4 bv = *(const float4*)(bz + jb);
                float4 o;
                o.x = fmaxf(bv.x + u0 * w0.x + u1 * w1.x, 0.0f);
                o.y = fmaxf(bv.y + u0 * w0.y + u1 * w1.y, 0.0f);
                o.z = fmaxf(bv.z + u0 * w0.z + u1 * w1.z, 0.0f);
                o.w = fmaxf(bv.w + u0 * w0.w + u1 * w1.w, 0.0f);
                *(float4*)(out + (size_t)n2 * HID + jb) = o;
            }
        }
    } else if (bid < NBKZ + NBKO) {       // outdoor: 64 nodes/block, ch=3
        int n0 = (bid - NBKZ) * 64;
        if (tid < 192) {
            int n = n0 + tid / 3, c = tid % 3;
            if (n < N_OUT) {
                int p = OUT_PAD_BASE + n;
                int rg = (p >> RSHIFT) - NBZ, i = p & (RANGE - 1);
                float sum = ws[WYO + 4 * n + c];
#pragma unroll
                for (int sl = 0; sl < SL_S; sl++)
                    sum += ws[WPSO + (size_t)(rg * SL_S + sl) * (RANGE * 3) + 3 * i + c];
                su[tid] = ws[WDINV + p] * sum;
            }
        }
        __syncthreads();
#pragma unroll
        for (int k = 0; k < 4; k++) {
            int f = tid + k * 256;
            int node = f >> 4, jb = (f & 15) << 2;
            int n2 = n0 + node;
            if (n2 < N_OUT) {
                float u0 = su[3 * node], u1 = su[3 * node + 1], u2 = su[3 * node + 2];
                float4 w0 = *(const float4*)(Wo + jb);
                float4 w1 = *(const float4*)(Wo + HID + jb);
                float4 w2 = *(const float4*)(Wo + 2 * HID + jb);
                float4 bv = *(const float4*)(bo + jb);
                float4 o;
                o.x = fmaxf(bv.x + u0 * w0.x + u1 * w1.x + u2 * w2.x, 0.0f);
                o.y = fmaxf(bv.y + u0 * w0.y + u1 * w1.y + u2 * w2.y, 0.0f);
                o.z = fmaxf(bv.z + u0 * w0.z + u1 * w1.z + u2 * w2.z, 0.0f);
                o.w = fmaxf(bv.w + u0 * w0.w + u1 * w1.w + u2 * w2.w, 0.0f);
                *(float4*)(out + (size_t)(N_ZONE + n2) * HID + jb) = o;
            }
        }
    } else {                              // ground: 256 nodes/block, ch=1
        int n0 = (bid - NBKZ - NBKO) * 256;
        int n = n0 + tid;
        if (n < N_GND) {
            int p = GND_PAD_BASE + n;
            int rg = (p >> RSHIFT) - NBZ - NBO, i = p & (RANGE - 1);
            float sum = ws[WYG + n];
#pragma unroll
            for (int sl = 0; sl < SL_S; sl++)
                sum += ws[WPSG + (size_t)(rg * SL_S + sl) * RANGE + i];
            su[tid] = ws[WDINV + p] * sum;
        }
        __syncthreads();
#pragma unroll
        for (int k = 0; k < 16; k++) {
            int f = tid + k * 256;
            int node = f >> 4, jb = (f & 15) << 2;
            int n2 = n0 + node;
            if (n2 < N_GND) {
                float u0 = su[node];
                float4 w0 = *(const float4*)(Wg + jb);
                float4 bv = *(const float4*)(bg + jb);
                float4 o;
                o.x = fmaxf(bv.x + u0 * w0.x, 0.0f);
                o.y = fmaxf(bv.y + u0 * w0.y, 0.0f);
                o.z = fmaxf(bv.z + u0 * w0.z, 0.0f);
                o.w = fmaxf(bv.w + u0 * w0.w, 0.0f);
                *(float4*)(out + (size_t)(N_ZONE + N_OUT + n2) * HID + jb) = o;
            }
        }
    }
}

// ---------------- fallback path (proven R1 kernels, 2.4 MB ws) ----------------
#define F_DEG_Z   0
#define F_DEG_O   (N_ZONE)
#define F_DEG_G   (N_ZONE + N_OUT)
#define F_DEG_TOT N_TOT
#define F_S_Z     F_DEG_TOT
#define F_S_O     (F_S_Z + N_ZONE * 2)
#define F_S_G     (F_S_O + N_OUT * 3)
#define F_TOT     (F_S_G + N_GND * 1)

__global__ void f_init(float* __restrict__ ws) {
    int i = blockIdx.x * blockDim.x + threadIdx.x;
    if (i < F_TOT) ws[i] = (i < F_DEG_TOT) ? 1.0f : 0.0f;
}
__global__ void f_deg(const int* __restrict__ eiz, const float* __restrict__ wz,
                      const int* __restrict__ eio, const float* __restrict__ wo,
                      const int* __restrict__ eig, const float* __restrict__ wg,
                      float* __restrict__ ws) {
    int t = blockIdx.x * blockDim.x + threadIdx.x;
    if (t < E_ZONE) atomicAdd(ws + F_DEG_Z + eiz[E_ZONE + t], wz[t]);
    else if (t < E_ZONE + E_OUT) { int e = t - E_ZONE; atomicAdd(ws + F_DEG_O + eio[E_OUT + e], wo[e]); }
    else if (t < E_ZONE + E_OUT + E_GND) { int e = t - E_ZONE - E_OUT; atomicAdd(ws + F_DEG_G + eig[E_GND + e], wg[e]); }
}
__global__ void f_dinv(float* __restrict__ ws) {
    int i = blockIdx.x * blockDim.x + threadIdx.x;
    if (i < F_DEG_TOT) ws[i] = 1.0f / sqrtf(ws[i]);
}
__global__ void f_scatter(const int* __restrict__ eiz, const float* __restrict__ wz, const float* __restrict__ xz,
                          const int* __restrict__ eio, const float* __restrict__ wo, const float* __restrict__ xo,
                          const int* __restrict__ eig, const float* __restrict__ wg, const float* __restrict__ xg,
                          float* __restrict__ ws) {
    int t = blockIdx.x * blockDim.x + threadIdx.x;
    if (t < E_ZONE) {
        int row = eiz[t], col = eiz[E_ZONE + t];
        float n = ws[F_DEG_Z + row] * wz[t] * ws[F_DEG_Z + col];
        atomicAdd(ws + F_S_Z + col * 2 + 0, n * xz[row * 2 + 0]);
        atomicAdd(ws + F_S_Z + col * 2 + 1, n * xz[row * 2 + 1]);
    } else if (t < E_ZONE + E_OUT) {
        int e = t - E_ZONE;
        int row = eio[e], col = eio[E_OUT + e];
        float n = ws[F_DEG_O + row] * wo[e] * ws[F_DEG_O + col];
        atomicAdd(ws + F_S_O + col * 3 + 0, n * xo[row * 3 + 0]);
        atomicAdd(ws + F_S_O + col * 3 + 1, n * xo[row * 3 + 1]);
        atomicAdd(ws + F_S_O + col * 3 + 2, n * xo[row * 3 + 2]);
    } else if (t < E_ZONE + E_OUT + E_GND) {
        int e = t - E_ZONE - E_OUT;
        int row = eig[e], col = eig[E_GND + e];
        float n = ws[F_DEG_G + row] * wg[e] * ws[F_DEG_G + col];
        atomicAdd(ws + F_S_G + col, n * xg[row]);
    }
}
__global__ void f_final(const float* __restrict__ ws,
                        const float* __restrict__ xz, const float* __restrict__ Wz, const float* __restrict__ bz,
                        const float* __restrict__ xo, const float* __restrict__ Wo, const float* __restrict__ bo,
                        const float* __restrict__ xg, const float* __restrict__ Wg, const float* __restrict__ bg,
                        float* __restrict__ out) {
    int t = blockIdx.x * blockDim.x + threadIdx.x;
    const int TZ = N_ZONE * HID, TO = TZ + N_OUT * HID, TG = TO + N_GND * HID;
    if (t < TZ) {
        int i = t >> 6, j = t & 63;
        float di = ws[F_DEG_Z + i], d2 = di * di;
        float t0 = ws[F_S_Z + i * 2 + 0] + d2 * xz[i * 2 + 0];
        float t1 = ws[F_S_Z + i * 2 + 1] + d2 * xz[i * 2 + 1];
        out[t] = fmaxf(bz[j] + t0 * Wz[j] + t1 * Wz[HID + j], 0.0f);
    } else if (t < TO) {
        int u = t - TZ;
        int i = u >> 6, j = u & 63;
        float di = ws[F_DEG_O + i], d2 = di * di;
        float t0 = ws[F_S_O + i * 3 + 0] + d2 * xo[i * 3 + 0];
        float t1 = ws[F_S_O + i * 3 + 1] + d2 * xo[i * 3 + 1];
        float t2 = ws[F_S_O + i * 3 + 2] + d2 * xo[i * 3 + 2];
        out[t] = fmaxf(bo[j] + t0 * Wo[j] + t1 * Wo[HID + j] + t2 * Wo[2 * HID + j], 0.0f);
    } else if (t < TG) {
        int u = t - TO;
        int i = u >> 6, j = u & 63;
        float di = ws[F_DEG_G + i], d2 = di * di;
        float t0 = ws[F_S_G + i] + d2 * xg[i];
        out[t] = fmaxf(bg[j] + t0 * Wg[j], 0.0f);
    }
}

extern "C" void kernel_launch(void* const* d_in, const int* in_sizes, int n_in,
                              void* d_out, int out_size, void* d_ws, size_t ws_size,
                              hipStream_t stream) {
    const float* xz = (const float*)d_in[0];
    const float* xo = (const float*)d_in[1];
    const float* xg = (const float*)d_in[2];
    const int*  eiz = (const int*)d_in[3];
    const int*  eio = (const int*)d_in[4];
    const int*  eig = (const int*)d_in[5];
    const float* Wz = (const float*)d_in[6];
    const float* Wo = (const float*)d_in[7];
    const float* Wg = (const float*)d_in[8];
    const float* bz = (const float*)d_in[9];
    const float* bo = (const float*)d_in[10];
    const float* bg = (const float*)d_in[11];
    const float* wz = (const float*)d_in[12];
    const float* wo = (const float*)d_in[13];
    const float* wg = (const float*)d_in[14];
    float* out = (float*)d_out;
    float* ws  = (float*)d_ws;

    const int B = 256;

    if (ws_size >= FAST_WS_BYTES) {
        unsigned* cur = (unsigned*)(ws + WCUR);
        uint2* rec = (uint2*)(ws + WREC);
        hipMemsetAsync(cur, 0, 128 * 4, stream);
        k_bin<<<NCHUNK, B, 0, stream>>>(eiz, wz, eio, wo, eig, wg, cur, rec);
        k_degp<<<NBUCKET * SL_D, B, 0, stream>>>(rec, cur, ws + WPDEG);
        k_dinvy<<<(PAD_TOT + B - 1) / B, B, 0, stream>>>(xz, xo, xg, ws);
        k_sp<<<NBUCKET * SL_S, B, 0, stream>>>(ws);
        k_fin3<<<NBKZ + NBKO + NBKG, B, 0, stream>>>(ws, Wz, bz, Wo, bo, Wg, bg, out);
    } else {
        const int E_TOT = E_TOTAL, OUT_TOT = N_TOT * HID;
        f_init<<<(F_TOT + B - 1) / B, B, 0, stream>>>(ws);
        f_deg<<<(E_TOT + B - 1) / B, B, 0, stream>>>(eiz, wz, eio, wo, eig, wg, ws);
        f_dinv<<<(F_DEG_TOT + B - 1) / B, B, 0, stream>>>(ws);
        f_scatter<<<(E_TOT + B - 1) / B, B, 0, stream>>>(eiz, wz, xz, eio, wo, xo, eig, wg, xg, ws);
        f_final<<<(OUT_TOT + B - 1) / B, B, 0, stream>>>(ws, xz, Wz, bz, xo, Wo, bo, xg, Wg, bg, out);
    }
}